// Round 1
// baseline (16360.559 us; speedup 1.0000x reference)
//
#include <hip/hip_runtime.h>
#include <stdint.h>

#define NN 4096
#define DF 128
#define NBINS (1 << 22)
#define CHUNK 4096
#define NCHUNKS (NBINS / CHUNK)

// ---------- helpers ----------
__device__ __forceinline__ unsigned bin_of(float v, float scale) {
  if (v < 0.f) v = 0.f;
  unsigned b = (unsigned)(v * scale);
  return b >= (unsigned)NBINS ? (unsigned)(NBINS - 1) : b;
}

// ---------- row squared norms for both graphs ----------
__global__ void k_rownorm(const float* __restrict__ x1, const float* __restrict__ x2,
                          float* __restrict__ sq) {
  int i = blockIdx.x * blockDim.x + threadIdx.x;
  if (i >= 2 * NN) return;
  const float* x = (i < NN) ? x1 : x2;
  int r = i & (NN - 1);
  const float* row = x + (size_t)r * DF;
  float s = 0.f;
  for (int k = 0; k < DF; ++k) s += row[k] * row[k];
  sq[i] = s;
}

// ---------- distance matrix: D = sqrt(relu(sq_i + sq_j - 2 x.xT)), + cap=max ----------
__global__ __launch_bounds__(256) void k_dist(const float* __restrict__ x1,
                                              const float* __restrict__ x2,
                                              const float* __restrict__ sq,
                                              float* __restrict__ Dbase,
                                              unsigned* __restrict__ caps) {
  int g = blockIdx.z;
  const float* x = g ? x2 : x1;
  const float* sqg = sq + g * NN;
  float* D = Dbase + (size_t)g * NN * NN;
  __shared__ float As[64][33];
  __shared__ float Bs[64][33];
  int i0 = blockIdx.y * 64, j0 = blockIdx.x * 64;
  int t = threadIdx.x;
  int tx = t & 15, ty = t >> 4;
  float acc[4][4];
  for (int r = 0; r < 4; ++r)
    for (int c = 0; c < 4; ++c) acc[r][c] = 0.f;
  for (int kc = 0; kc < DF; kc += 32) {
    for (int s = 0; s < 8; ++s) {
      int idx = t + 256 * s;
      int r = idx >> 5, k = idx & 31;
      As[r][k] = x[(size_t)(i0 + r) * DF + kc + k];
      Bs[r][k] = x[(size_t)(j0 + r) * DF + kc + k];
    }
    __syncthreads();
    for (int k = 0; k < 32; ++k) {
      float a[4], b[4];
      for (int r = 0; r < 4; ++r) a[r] = As[ty * 4 + r][k];
      for (int c = 0; c < 4; ++c) b[c] = Bs[tx * 4 + c][k];
      for (int r = 0; r < 4; ++r)
        for (int c = 0; c < 4; ++c) acc[r][c] += a[r] * b[c];
    }
    __syncthreads();
  }
  float mx = 0.f;
  for (int r = 0; r < 4; ++r) {
    int i = i0 + ty * 4 + r;
    union { float a[4]; float4 v; } dv;
    for (int c = 0; c < 4; ++c) {
      int j = j0 + tx * 4 + c;
      float d2 = sqg[i] + sqg[j] - 2.f * acc[r][c];
      d2 = fmaxf(d2, 0.f);
      float d = (d2 > 1e-12f) ? sqrtf(d2) : 0.f;
      dv.a[c] = d;
      mx = fmaxf(mx, d);
    }
    *(float4*)(D + (size_t)i * NN + j0 + tx * 4) = dv.v;
  }
  for (int off = 32; off > 0; off >>= 1) mx = fmaxf(mx, __shfl_down(mx, off, 64));
  __shared__ float wmax[4];
  if ((t & 63) == 0) wmax[t >> 6] = mx;
  __syncthreads();
  if (t == 0) {
    float m = fmaxf(fmaxf(wmax[0], wmax[1]), fmaxf(wmax[2], wmax[3]));
    atomicMax(&caps[g], __float_as_uint(m));
  }
}

// ---------- Prim MST: one block per graph, records the 4095 edge weights ----------
__global__ __launch_bounds__(512) void k_prim(const float* __restrict__ Dbase,
                                              float* __restrict__ twbase) {
  int g = blockIdx.x;
  const float* D = Dbase + (size_t)g * NN * NN;
  float* tw = twbase + g * (NN - 1);
  __shared__ float mind[NN];
  __shared__ unsigned vis[NN / 32];
  __shared__ unsigned long long wmin[8];
  __shared__ int shj;
  int t = threadIdx.x;
  for (int e = t; e < NN; e += 512) mind[e] = D[e];  // row 0
  for (int e = t; e < NN / 32; e += 512) vis[e] = 0u;
  if (t == 0) vis[0] = 1u;
  __syncthreads();
  for (int it = 0; it < NN - 1; ++it) {
    // argmin over unvisited (pack value bits | index; distances >= 0 so uint order == float order)
    unsigned long long best = ~0ull;
    for (int e = t; e < NN; e += 512) {
      if (!((vis[e >> 5] >> (e & 31)) & 1u)) {
        unsigned long long key =
            ((unsigned long long)__float_as_uint(mind[e]) << 32) | (unsigned)e;
        if (key < best) best = key;
      }
    }
    for (int off = 32; off > 0; off >>= 1) {
      unsigned long long o = __shfl_down(best, off, 64);
      if (o < best) best = o;
    }
    if ((t & 63) == 0) wmin[t >> 6] = best;
    __syncthreads();
    if (t == 0) {
      unsigned long long bb = wmin[0];
      for (int w = 1; w < 8; ++w)
        if (wmin[w] < bb) bb = wmin[w];
      int j = (int)(bb & 0xffffffffull);
      shj = j;
      vis[j >> 5] |= (1u << (j & 31));
      tw[it] = __uint_as_float((unsigned)(bb >> 32));
    }
    __syncthreads();
    int j = shj;
    const float* row = D + (size_t)j * NN;
    for (int e = t; e < NN; e += 512) {
      float d = row[e];
      if (d < mind[e] && !((vis[e >> 5] >> (e & 31)) & 1u)) mind[e] = d;
    }
    __syncthreads();
  }
}

// ---------- histogram of persistence values over the full (doubled) matrix ----------
__global__ __launch_bounds__(256) void k_hist(const float* __restrict__ Dbase,
                                              const unsigned* __restrict__ caps,
                                              unsigned* __restrict__ histbase) {
  int g = blockIdx.y;
  const float* D = Dbase + (size_t)g * NN * NN;
  unsigned* hist = histbase + (size_t)g * NBINS;
  float cap = __uint_as_float(caps[g]);
  float capmax = fmaxf(__uint_as_float(caps[0]), __uint_as_float(caps[1]));
  float scale = (float)NBINS / capmax;
  int stride = gridDim.x * blockDim.x;
  for (int idx = blockIdx.x * blockDim.x + threadIdx.x; idx < NN * NN; idx += stride) {
    int i = idx >> 12, j = idx & (NN - 1);
    if (i == j) continue;
    float v = cap - D[idx];
    atomicAdd(&hist[bin_of(v, scale)], 1u);
  }
}

// ---------- move tree edges to persistence 0 (doubled counts: -2 / +2) ----------
__global__ void k_treefix(const float* __restrict__ twbase, const unsigned* __restrict__ caps,
                          unsigned* __restrict__ histbase) {
  int g = blockIdx.y;
  unsigned* hist = histbase + (size_t)g * NBINS;
  float cap = __uint_as_float(caps[g]);
  float capmax = fmaxf(__uint_as_float(caps[0]), __uint_as_float(caps[1]));
  float scale = (float)NBINS / capmax;
  int idx = blockIdx.x * blockDim.x + threadIdx.x;
  if (idx < NN - 1) {
    float w = twbase[g * (NN - 1) + idx];
    atomicSub(&hist[bin_of(cap - w, scale)], 2u);
    atomicAdd(&hist[0], 2u);
  }
}

// ---------- scan phase A: per-chunk sums of (H1 - H2) ----------
__global__ __launch_bounds__(256) void k_blocksum(const unsigned* __restrict__ h1,
                                                  const unsigned* __restrict__ h2,
                                                  long long* __restrict__ csum) {
  int b = blockIdx.x, t = threadIdx.x;
  int base = b * CHUNK;
  long long s = 0;
  for (int i = t; i < CHUNK; i += 256) s += (long long)(int)(h1[base + i] - h2[base + i]);
  for (int off = 32; off > 0; off >>= 1) s += __shfl_down(s, off, 64);
  __shared__ long long wsum[4];
  if ((t & 63) == 0) wsum[t >> 6] = s;
  __syncthreads();
  if (t == 0) csum[b] = wsum[0] + wsum[1] + wsum[2] + wsum[3];
}

// ---------- scan phase B: exclusive scan of chunk sums (single block) ----------
__global__ __launch_bounds__(1024) void k_scanoff(const long long* __restrict__ csum,
                                                  long long* __restrict__ coffs) {
  __shared__ long long sh[NCHUNKS];
  int t = threadIdx.x;
  sh[t] = csum[t];
  __syncthreads();
  for (int off = 1; off < NCHUNKS; off <<= 1) {
    long long v = (t >= off) ? sh[t - off] : 0;
    __syncthreads();
    sh[t] += v;
    __syncthreads();
  }
  coffs[t] = sh[t] - csum[t];
}

// ---------- scan phase C: sum |running prefix| exactly (u64) ----------
__global__ __launch_bounds__(256) void k_final(const unsigned* __restrict__ h1,
                                               const unsigned* __restrict__ h2,
                                               const long long* __restrict__ coffs,
                                               unsigned long long* __restrict__ acc) {
  int b = blockIdx.x, t = threadIdx.x;
  int base = b * CHUNK + t * 16;
  long long v[16];
  long long tsum = 0;
  for (int r = 0; r < 16; ++r) {
    v[r] = (long long)(int)(h1[base + r] - h2[base + r]);
    tsum += v[r];
  }
  int lane = t & 63, wid = t >> 6;
  long long incl = tsum;
  for (int off = 1; off < 64; off <<= 1) {
    long long o = __shfl_up(incl, off, 64);
    if (lane >= off) incl += o;
  }
  __shared__ long long wtot[4];
  if (lane == 63) wtot[wid] = incl;
  __syncthreads();
  long long woff = 0;
  for (int w = 0; w < wid; ++w) woff += wtot[w];
  long long run = coffs[b] + woff + (incl - tsum);
  unsigned long long local = 0;
  for (int r = 0; r < 16; ++r) {
    run += v[r];
    local += (unsigned long long)(run < 0 ? -run : run);
  }
  for (int off = 32; off > 0; off >>= 1) local += __shfl_down(local, off, 64);
  __shared__ unsigned long long wl[4];
  if (lane == 0) wl[wid] = local;
  __syncthreads();
  if (t == 0) atomicAdd(acc, wl[0] + wl[1] + wl[2] + wl[3]);
}

// ---------- output ----------
__global__ void k_out(const unsigned long long* __restrict__ acc,
                      const unsigned* __restrict__ caps, float* __restrict__ out) {
  float capmax = fmaxf(__uint_as_float(caps[0]), __uint_as_float(caps[1]));
  double dt = (double)capmax / (double)NBINS;
  out[0] = (float)((double)(*acc) * dt * 0.5);  // 0.5: symmetric double-count
}

__global__ void k_fail(float* out) { out[0] = -1234567.0f; }  // ws too small sentinel

extern "C" void kernel_launch(void* const* d_in, const int* in_sizes, int n_in,
                              void* d_out, int out_size, void* d_ws, size_t ws_size,
                              hipStream_t stream) {
  const float* x1 = (const float*)d_in[0];
  const float* x2 = (const float*)d_in[2];
  float* out = (float*)d_out;
  char* ws = (char*)d_ws;

  const size_t offD = 0;                                   // 2 * 64 MB distance matrices
  const size_t offH = 2ull * NN * NN * 4ull;               // 2 * 16 MB histograms
  const size_t offHdr = offH + 2ull * (size_t)NBINS * 4ull; // caps(8) + acc(8) + pad
  const size_t offSq = offHdr + 64;                        // 2*N row norms
  const size_t offTw = offSq + 2ull * NN * 4ull;           // 2*(N-1) tree weights
  const size_t offCs = (offTw + 2ull * (NN - 1) * 4ull + 7ull) & ~7ull;
  const size_t offCo = offCs + (size_t)NCHUNKS * 8ull;
  const size_t needed = offCo + (size_t)NCHUNKS * 8ull;
  if (ws_size < needed) {
    hipLaunchKernelGGL(k_fail, dim3(1), dim3(1), 0, stream, out);
    return;
  }

  float* Dbase = (float*)(ws + offD);
  unsigned* hist = (unsigned*)(ws + offH);
  unsigned* caps = (unsigned*)(ws + offHdr);
  unsigned long long* acc = (unsigned long long*)(ws + offHdr + 8);
  float* sq = (float*)(ws + offSq);
  float* tw = (float*)(ws + offTw);
  long long* csum = (long long*)(ws + offCs);
  long long* coffs = (long long*)(ws + offCo);

  // zero histograms + caps + acc (ws is re-poisoned 0xAA before every call)
  hipMemsetAsync(ws + offH, 0, 2ull * (size_t)NBINS * 4ull + 64, stream);

  hipLaunchKernelGGL(k_rownorm, dim3((2 * NN + 255) / 256), dim3(256), 0, stream, x1, x2, sq);
  hipLaunchKernelGGL(k_dist, dim3(64, 64, 2), dim3(256), 0, stream, x1, x2, sq, Dbase, caps);
  hipLaunchKernelGGL(k_prim, dim3(2), dim3(512), 0, stream, Dbase, tw);
  hipLaunchKernelGGL(k_hist, dim3(4096, 2), dim3(256), 0, stream, Dbase, caps, hist);
  hipLaunchKernelGGL(k_treefix, dim3(16, 2), dim3(256), 0, stream, tw, caps, hist);
  hipLaunchKernelGGL(k_blocksum, dim3(NCHUNKS), dim3(256), 0, stream, hist, hist + NBINS, csum);
  hipLaunchKernelGGL(k_scanoff, dim3(1), dim3(NCHUNKS), 0, stream, csum, coffs);
  hipLaunchKernelGGL(k_final, dim3(NCHUNKS), dim3(256), 0, stream, hist, hist + NBINS, coffs, acc);
  hipLaunchKernelGGL(k_out, dim3(1), dim3(1), 0, stream, acc, caps, out);
}

// Round 2
// 1867.056 us; speedup vs baseline: 8.7628x; 8.7628x over previous
//
#include <hip/hip_runtime.h>
#include <stdint.h>

#define NN 4096
#define DF 128
#define NBINS (1 << 22)
#define CHUNK 4096
#define NCHUNKS (NBINS / CHUNK)
#define BORUVKA_ROUNDS 12

// ---------- helpers ----------
__device__ __forceinline__ unsigned bin_of(float v, float scale) {
  if (v < 0.f) v = 0.f;
  unsigned b = (unsigned)(v * scale);
  return b >= (unsigned)NBINS ? (unsigned)(NBINS - 1) : b;
}

// ---------- row squared norms for both graphs ----------
__global__ void k_rownorm(const float* __restrict__ x1, const float* __restrict__ x2,
                          float* __restrict__ sq) {
  int i = blockIdx.x * blockDim.x + threadIdx.x;
  if (i >= 2 * NN) return;
  const float* x = (i < NN) ? x1 : x2;
  int r = i & (NN - 1);
  const float* row = x + (size_t)r * DF;
  float s = 0.f;
  for (int k = 0; k < DF; ++k) s += row[k] * row[k];
  sq[i] = s;
}

// ---------- distance matrix: D = sqrt(relu(sq_i + sq_j - 2 x.xT)), + cap=max ----------
__global__ __launch_bounds__(256) void k_dist(const float* __restrict__ x1,
                                              const float* __restrict__ x2,
                                              const float* __restrict__ sq,
                                              float* __restrict__ Dbase,
                                              unsigned* __restrict__ caps) {
  int g = blockIdx.z;
  const float* x = g ? x2 : x1;
  const float* sqg = sq + g * NN;
  float* D = Dbase + (size_t)g * NN * NN;
  __shared__ float As[64][33];
  __shared__ float Bs[64][33];
  int i0 = blockIdx.y * 64, j0 = blockIdx.x * 64;
  int t = threadIdx.x;
  int tx = t & 15, ty = t >> 4;
  float acc[4][4];
  for (int r = 0; r < 4; ++r)
    for (int c = 0; c < 4; ++c) acc[r][c] = 0.f;
  for (int kc = 0; kc < DF; kc += 32) {
    for (int s = 0; s < 8; ++s) {
      int idx = t + 256 * s;
      int r = idx >> 5, k = idx & 31;
      As[r][k] = x[(size_t)(i0 + r) * DF + kc + k];
      Bs[r][k] = x[(size_t)(j0 + r) * DF + kc + k];
    }
    __syncthreads();
    for (int k = 0; k < 32; ++k) {
      float a[4], b[4];
      for (int r = 0; r < 4; ++r) a[r] = As[ty * 4 + r][k];
      for (int c = 0; c < 4; ++c) b[c] = Bs[tx * 4 + c][k];
      for (int r = 0; r < 4; ++r)
        for (int c = 0; c < 4; ++c) acc[r][c] += a[r] * b[c];
    }
    __syncthreads();
  }
  float mx = 0.f;
  for (int r = 0; r < 4; ++r) {
    int i = i0 + ty * 4 + r;
    union { float a[4]; float4 v; } dv;
    for (int c = 0; c < 4; ++c) {
      int j = j0 + tx * 4 + c;
      float d2 = sqg[i] + sqg[j] - 2.f * acc[r][c];
      d2 = fmaxf(d2, 0.f);
      float d = (d2 > 1e-12f) ? sqrtf(d2) : 0.f;
      dv.a[c] = d;
      mx = fmaxf(mx, d);
    }
    *(float4*)(D + (size_t)i * NN + j0 + tx * 4) = dv.v;
  }
  for (int off = 32; off > 0; off >>= 1) mx = fmaxf(mx, __shfl_down(mx, off, 64));
  __shared__ float wmax[4];
  if ((t & 63) == 0) wmax[t >> 6] = mx;
  __syncthreads();
  if (t == 0) {
    float m = fmaxf(fmaxf(wmax[0], wmax[1]), fmaxf(wmax[2], wmax[3]));
    atomicMax(&caps[g], __float_as_uint(m));
  }
}

// ---------- Boruvka init ----------
__global__ void k_binit(int* __restrict__ comp, unsigned long long* __restrict__ compbest,
                        int* __restrict__ mstcnt, int* __restrict__ ncomp) {
  int i = blockIdx.x * blockDim.x + threadIdx.x;
  if (i >= 2 * NN) return;
  comp[i] = i & (NN - 1);
  compbest[i] = ~0ull;
  if ((i & (NN - 1)) == 0) {
    mstcnt[i >> 12] = 0;
    ncomp[i >> 12] = NN;
  }
}

// ---------- Boruvka step 1: per-row min edge leaving own component ----------
// key = (weight_bits << 24) | (v << 12) | j  -- globally unique => hook graph
// has only 2-cycles; uint order of weight_bits == float order (weights >= 0).
__global__ __launch_bounds__(256) void k_minedge(const float* __restrict__ Dbase,
                                                 const int* __restrict__ comp_base,
                                                 unsigned long long* __restrict__ compbest_base,
                                                 const int* __restrict__ ncomp) {
  int g = blockIdx.y;
  if (ncomp[g] == 1) return;  // converged: dead round, near-free
  int v = blockIdx.x;
  const float* row = Dbase + ((size_t)g * NN + (size_t)v) * NN;
  const int* comp = comp_base + g * NN;
  unsigned long long* cbest = compbest_base + (size_t)g * NN;
  int cv = comp[v];
  int t = threadIdx.x;
  unsigned long long best = ~0ull;
  for (int j = t; j < NN; j += 256) {
    if (comp[j] != cv) {
      unsigned long long key = ((unsigned long long)__float_as_uint(row[j]) << 24) |
                               ((unsigned)v << 12) | (unsigned)j;
      if (key < best) best = key;
    }
  }
  for (int off = 32; off > 0; off >>= 1) {
    unsigned long long o = __shfl_down(best, off, 64);
    if (o < best) best = o;
  }
  __shared__ unsigned long long wmin[4];
  if ((t & 63) == 0) wmin[t >> 6] = best;
  __syncthreads();
  if (t == 0) {
    unsigned long long bb = wmin[0];
    for (int w = 1; w < 4; ++w)
      if (wmin[w] < bb) bb = wmin[w];
    if (bb != ~0ull) atomicMin(&cbest[cv], bb);
  }
}

// ---------- Boruvka step 2: hook, break 2-cycles, emit MST weights,
//            pointer-jump, relabel vertices, recount components, reset ----------
__global__ __launch_bounds__(1024) void k_hook(unsigned long long* __restrict__ compbest_base,
                                               int* __restrict__ comp_base,
                                               float* __restrict__ mstw_base,
                                               int* __restrict__ mstcnt,
                                               int* __restrict__ ncomp) {
  int g = blockIdx.x;
  if (ncomp[g] == 1) return;
  unsigned long long* cb = compbest_base + (size_t)g * NN;
  int* comp = comp_base + g * NN;
  float* mstw = mstw_base + g * (NN - 1);
  __shared__ int par[NN];
  __shared__ unsigned char live[NN];
  __shared__ int newcnt;
  int t = threadIdx.x;
  if (t == 0) newcnt = 0;
  // fill: hook each live component to the component of its min-edge target
  for (int c = t; c < NN; c += 1024) {
    unsigned long long key = cb[c];
    bool a = (key != ~0ull);
    live[c] = a ? 1 : 0;
    int p = c;
    if (a) {
      int j = (int)(key & 0xfffull);
      p = comp[j];
    }
    par[c] = p;
  }
  __syncthreads();
  // break 2-cycles: smaller label becomes root (race-safe: each thread writes only its own slots)
  for (int c = t; c < NN; c += 1024) {
    int p = par[c];
    if (p != c && par[p] == c && c < p) par[c] = c;
  }
  __syncthreads();
  // collect one MST edge weight per hooked component
  for (int c = t; c < NN; c += 1024) {
    if (live[c] && par[c] != c) {
      unsigned long long key = cb[c];
      float w = __uint_as_float((unsigned)(key >> 24));
      int slot = atomicAdd(&mstcnt[g], 1);
      mstw[slot] = w;
    }
  }
  __syncthreads();
  // pointer jumping: depth <= 4096, 12 doublings flatten fully
  for (int it = 0; it < 12; ++it) {
    int np[NN / 1024];
    for (int c = t, k = 0; c < NN; c += 1024, ++k) np[k] = par[par[c]];
    __syncthreads();
    for (int c = t, k = 0; c < NN; c += 1024, ++k) par[c] = np[k];
    __syncthreads();
  }
  // recount components
  int cnt = 0;
  for (int c = t; c < NN; c += 1024)
    if (live[c] && par[c] == c) cnt++;
  for (int off = 32; off > 0; off >>= 1) cnt += __shfl_down(cnt, off, 64);
  if ((t & 63) == 0 && cnt) atomicAdd(&newcnt, cnt);
  // relabel vertices + reset compbest
  for (int v = t; v < NN; v += 1024) comp[v] = par[comp[v]];
  for (int c = t; c < NN; c += 1024) cb[c] = ~0ull;
  __syncthreads();
  if (t == 0) ncomp[g] = newcnt;
}

// ---------- histogram of persistence values over the full (doubled) matrix ----------
__global__ __launch_bounds__(256) void k_hist(const float* __restrict__ Dbase,
                                              const unsigned* __restrict__ caps,
                                              unsigned* __restrict__ histbase) {
  int g = blockIdx.y;
  const float* D = Dbase + (size_t)g * NN * NN;
  unsigned* hist = histbase + (size_t)g * NBINS;
  float cap = __uint_as_float(caps[g]);
  float capmax = fmaxf(__uint_as_float(caps[0]), __uint_as_float(caps[1]));
  float scale = (float)NBINS / capmax;
  int stride = gridDim.x * blockDim.x;
  for (int idx = blockIdx.x * blockDim.x + threadIdx.x; idx < NN * NN; idx += stride) {
    int i = idx >> 12, j = idx & (NN - 1);
    if (i == j) continue;
    float v = cap - D[idx];
    atomicAdd(&hist[bin_of(v, scale)], 1u);
  }
}

// ---------- move tree edges to persistence 0 (doubled counts: -2 / +2) ----------
__global__ void k_treefix(const float* __restrict__ twbase, const unsigned* __restrict__ caps,
                          unsigned* __restrict__ histbase) {
  int g = blockIdx.y;
  unsigned* hist = histbase + (size_t)g * NBINS;
  float cap = __uint_as_float(caps[g]);
  float capmax = fmaxf(__uint_as_float(caps[0]), __uint_as_float(caps[1]));
  float scale = (float)NBINS / capmax;
  int idx = blockIdx.x * blockDim.x + threadIdx.x;
  if (idx < NN - 1) {
    float w = twbase[g * (NN - 1) + idx];
    atomicSub(&hist[bin_of(cap - w, scale)], 2u);
    atomicAdd(&hist[0], 2u);
  }
}

// ---------- scan phase A: per-chunk sums of (H1 - H2) ----------
__global__ __launch_bounds__(256) void k_blocksum(const unsigned* __restrict__ h1,
                                                  const unsigned* __restrict__ h2,
                                                  long long* __restrict__ csum) {
  int b = blockIdx.x, t = threadIdx.x;
  int base = b * CHUNK;
  long long s = 0;
  for (int i = t; i < CHUNK; i += 256) s += (long long)(int)(h1[base + i] - h2[base + i]);
  for (int off = 32; off > 0; off >>= 1) s += __shfl_down(s, off, 64);
  __shared__ long long wsum[4];
  if ((t & 63) == 0) wsum[t >> 6] = s;
  __syncthreads();
  if (t == 0) csum[b] = wsum[0] + wsum[1] + wsum[2] + wsum[3];
}

// ---------- scan phase B: exclusive scan of chunk sums (single block) ----------
__global__ __launch_bounds__(1024) void k_scanoff(const long long* __restrict__ csum,
                                                  long long* __restrict__ coffs) {
  __shared__ long long sh[NCHUNKS];
  int t = threadIdx.x;
  sh[t] = csum[t];
  __syncthreads();
  for (int off = 1; off < NCHUNKS; off <<= 1) {
    long long v = (t >= off) ? sh[t - off] : 0;
    __syncthreads();
    sh[t] += v;
    __syncthreads();
  }
  coffs[t] = sh[t] - csum[t];
}

// ---------- scan phase C: sum |running prefix| exactly (u64) ----------
__global__ __launch_bounds__(256) void k_final(const unsigned* __restrict__ h1,
                                               const unsigned* __restrict__ h2,
                                               const long long* __restrict__ coffs,
                                               unsigned long long* __restrict__ acc) {
  int b = blockIdx.x, t = threadIdx.x;
  int base = b * CHUNK + t * 16;
  long long v[16];
  long long tsum = 0;
  for (int r = 0; r < 16; ++r) {
    v[r] = (long long)(int)(h1[base + r] - h2[base + r]);
    tsum += v[r];
  }
  int lane = t & 63, wid = t >> 6;
  long long incl = tsum;
  for (int off = 1; off < 64; off <<= 1) {
    long long o = __shfl_up(incl, off, 64);
    if (lane >= off) incl += o;
  }
  __shared__ long long wtot[4];
  if (lane == 63) wtot[wid] = incl;
  __syncthreads();
  long long woff = 0;
  for (int w = 0; w < wid; ++w) woff += wtot[w];
  long long run = coffs[b] + woff + (incl - tsum);
  unsigned long long local = 0;
  for (int r = 0; r < 16; ++r) {
    run += v[r];
    local += (unsigned long long)(run < 0 ? -run : run);
  }
  for (int off = 32; off > 0; off >>= 1) local += __shfl_down(local, off, 64);
  __shared__ unsigned long long wl[4];
  if (lane == 0) wl[wid] = local;
  __syncthreads();
  if (t == 0) atomicAdd(acc, wl[0] + wl[1] + wl[2] + wl[3]);
}

// ---------- output ----------
__global__ void k_out(const unsigned long long* __restrict__ acc,
                      const unsigned* __restrict__ caps, float* __restrict__ out) {
  float capmax = fmaxf(__uint_as_float(caps[0]), __uint_as_float(caps[1]));
  double dt = (double)capmax / (double)NBINS;
  out[0] = (float)((double)(*acc) * dt * 0.5);  // 0.5: symmetric double-count
}

__global__ void k_fail(float* out) { out[0] = -1234567.0f; }  // ws too small sentinel

extern "C" void kernel_launch(void* const* d_in, const int* in_sizes, int n_in,
                              void* d_out, int out_size, void* d_ws, size_t ws_size,
                              hipStream_t stream) {
  const float* x1 = (const float*)d_in[0];
  const float* x2 = (const float*)d_in[2];
  float* out = (float*)d_out;
  char* ws = (char*)d_ws;

  const size_t offD = 0;                                    // 2 * 64 MB distance matrices
  const size_t offH = 2ull * NN * NN * 4ull;                // 2 * 16 MB histograms
  const size_t offHdr = offH + 2ull * (size_t)NBINS * 4ull; // caps(8) + acc(8) + pad
  const size_t offSq = offHdr + 64;                         // 2*N row norms
  const size_t offTw = offSq + 2ull * NN * 4ull;            // 2*(N-1) MST weights
  const size_t offCs = (offTw + 2ull * (NN - 1) * 4ull + 7ull) & ~7ull;
  const size_t offCo = offCs + (size_t)NCHUNKS * 8ull;
  const size_t offCb = offCo + (size_t)NCHUNKS * 8ull;      // compbest u64[2*NN]
  const size_t offCp = offCb + 2ull * NN * 8ull;            // comp int[2*NN]
  const size_t offMeta = offCp + 2ull * NN * 4ull;          // mstcnt[2], ncomp[2]
  const size_t needed = offMeta + 64;
  if (ws_size < needed) {
    hipLaunchKernelGGL(k_fail, dim3(1), dim3(1), 0, stream, out);
    return;
  }

  float* Dbase = (float*)(ws + offD);
  unsigned* hist = (unsigned*)(ws + offH);
  unsigned* caps = (unsigned*)(ws + offHdr);
  unsigned long long* acc = (unsigned long long*)(ws + offHdr + 8);
  float* sq = (float*)(ws + offSq);
  float* tw = (float*)(ws + offTw);
  long long* csum = (long long*)(ws + offCs);
  long long* coffs = (long long*)(ws + offCo);
  unsigned long long* compbest = (unsigned long long*)(ws + offCb);
  int* comp = (int*)(ws + offCp);
  int* mstcnt = (int*)(ws + offMeta);
  int* ncomp = (int*)(ws + offMeta + 8);

  // zero histograms + caps + acc (ws is re-poisoned 0xAA before every call)
  hipMemsetAsync(ws + offH, 0, 2ull * (size_t)NBINS * 4ull + 64, stream);

  hipLaunchKernelGGL(k_rownorm, dim3((2 * NN + 255) / 256), dim3(256), 0, stream, x1, x2, sq);
  hipLaunchKernelGGL(k_dist, dim3(64, 64, 2), dim3(256), 0, stream, x1, x2, sq, Dbase, caps);
  hipLaunchKernelGGL(k_binit, dim3((2 * NN + 255) / 256), dim3(256), 0, stream,
                     comp, compbest, mstcnt, ncomp);
  for (int r = 0; r < BORUVKA_ROUNDS; ++r) {
    hipLaunchKernelGGL(k_minedge, dim3(NN, 2), dim3(256), 0, stream,
                       Dbase, comp, compbest, ncomp);
    hipLaunchKernelGGL(k_hook, dim3(2), dim3(1024), 0, stream,
                       compbest, comp, tw, mstcnt, ncomp);
  }
  hipLaunchKernelGGL(k_hist, dim3(4096, 2), dim3(256), 0, stream, Dbase, caps, hist);
  hipLaunchKernelGGL(k_treefix, dim3(16, 2), dim3(256), 0, stream, tw, caps, hist);
  hipLaunchKernelGGL(k_blocksum, dim3(NCHUNKS), dim3(256), 0, stream, hist, hist + NBINS, csum);
  hipLaunchKernelGGL(k_scanoff, dim3(1), dim3(NCHUNKS), 0, stream, csum, coffs);
  hipLaunchKernelGGL(k_final, dim3(NCHUNKS), dim3(256), 0, stream, hist, hist + NBINS, coffs, acc);
  hipLaunchKernelGGL(k_out, dim3(1), dim3(1), 0, stream, acc, caps, out);
}

// Round 3
// 1171.343 us; speedup vs baseline: 13.9673x; 1.5939x over previous
//
#include <hip/hip_runtime.h>
#include <stdint.h>

#define NN 4096
#define DF 128
#define NBINS (1 << 22)
#define CHUNK 4096
#define NCHUNKS (NBINS / CHUNK)
#define BORUVKA_ROUNDS 12

typedef __attribute__((ext_vector_type(8))) short short8;
typedef __attribute__((ext_vector_type(4))) float floatx4;

// ---------- helpers ----------
__device__ __forceinline__ unsigned bin_of(float v, float scale) {
  if (v < 0.f) v = 0.f;
  unsigned b = (unsigned)(v * scale);
  return b >= (unsigned)NBINS ? (unsigned)(NBINS - 1) : b;
}

// ---------- row squared norms for both graphs (fp32, matches reference) ----------
__global__ void k_rownorm(const float* __restrict__ x1, const float* __restrict__ x2,
                          float* __restrict__ sq) {
  int i = blockIdx.x * blockDim.x + threadIdx.x;
  if (i >= 2 * NN) return;
  const float* x = (i < NN) ? x1 : x2;
  int r = i & (NN - 1);
  const float* row = x + (size_t)r * DF;
  float s = 0.f;
  for (int k = 0; k < DF; ++k) s += row[k] * row[k];
  sq[i] = s;
}

// ---------- split fp32 -> (hi, lo) bf16 for error-compensated MFMA ----------
__global__ void k_split(const float* __restrict__ x1, const float* __restrict__ x2,
                        unsigned short* __restrict__ xh, unsigned short* __restrict__ xl) {
  int i = blockIdx.x * blockDim.x + threadIdx.x;
  if (i >= 2 * NN * DF) return;
  const float* x = (i < NN * DF) ? x1 : x2;
  float v = x[i & (NN * DF - 1)];
  unsigned u = __float_as_uint(v);
  unsigned hu = u & 0xffff0000u;          // truncate to bf16
  float hf = __uint_as_float(hu);
  float lf = v - hf;                      // exact in fp32
  unsigned lu = __float_as_uint(lf) & 0xffff0000u;
  xh[i] = (unsigned short)(hu >> 16);
  xl[i] = (unsigned short)(lu >> 16);
}

// ---------- distance matrix via split-bf16 MFMA Gram ----------
// G ~= Hi.Hi^T + Hi.Lo^T + Lo.Hi^T  (abs err ~1e-4 on d2 -> ~1e-5 on d)
__global__ __launch_bounds__(256) void k_dist(const unsigned short* __restrict__ Xhi,
                                              const unsigned short* __restrict__ Xlo,
                                              const float* __restrict__ sq,
                                              float* __restrict__ Dbase,
                                              unsigned* __restrict__ caps) {
  int g = blockIdx.z;
  const unsigned short* xh = Xhi + (size_t)g * NN * DF;
  const unsigned short* xl = Xlo + (size_t)g * NN * DF;
  const float* sqg = sq + g * NN;
  float* D = Dbase + (size_t)g * NN * NN;
  __shared__ __align__(16) unsigned short Ah[64 * 32];
  __shared__ __align__(16) unsigned short Al[64 * 32];
  __shared__ __align__(16) unsigned short Bh[64 * 32];
  __shared__ __align__(16) unsigned short Bl[64 * 32];
  int i0 = blockIdx.y * 64, j0 = blockIdx.x * 64;
  int t = threadIdx.x;
  int w = t >> 6, lane = t & 63;
  int m = lane & 15, quad = lane >> 4;
  floatx4 acc[4];
  for (int s = 0; s < 4; ++s) acc[s] = (floatx4){0.f, 0.f, 0.f, 0.f};
  int srow = t >> 2, skp = (t & 3) * 8;
  for (int kc = 0; kc < DF; kc += 32) {
    if (kc) __syncthreads();
    *(short8*)&Ah[srow * 32 + skp] = *(const short8*)&xh[(size_t)(i0 + srow) * DF + kc + skp];
    *(short8*)&Al[srow * 32 + skp] = *(const short8*)&xl[(size_t)(i0 + srow) * DF + kc + skp];
    *(short8*)&Bh[srow * 32 + skp] = *(const short8*)&xh[(size_t)(j0 + srow) * DF + kc + skp];
    *(short8*)&Bl[srow * 32 + skp] = *(const short8*)&xl[(size_t)(j0 + srow) * DF + kc + skp];
    __syncthreads();
    short8 ah = *(const short8*)&Ah[(w * 16 + m) * 32 + quad * 8];
    short8 al = *(const short8*)&Al[(w * 16 + m) * 32 + quad * 8];
    for (int s = 0; s < 4; ++s) {
      short8 bh = *(const short8*)&Bh[(s * 16 + m) * 32 + quad * 8];
      short8 bl = *(const short8*)&Bl[(s * 16 + m) * 32 + quad * 8];
      acc[s] = __builtin_amdgcn_mfma_f32_16x16x32_bf16(ah, bh, acc[s], 0, 0, 0);
      acc[s] = __builtin_amdgcn_mfma_f32_16x16x32_bf16(ah, bl, acc[s], 0, 0, 0);
      acc[s] = __builtin_amdgcn_mfma_f32_16x16x32_bf16(al, bh, acc[s], 0, 0, 0);
    }
  }
  // C/D layout: col = lane&15 (j), row = quad*4 + reg (i)
  float mx = 0.f;
  int ib = i0 + w * 16 + quad * 4;
  for (int s = 0; s < 4; ++s) {
    int j = j0 + s * 16 + m;
    float sqj = sqg[j];
    for (int r = 0; r < 4; ++r) {
      int i = ib + r;
      float d2 = sqg[i] + sqj - 2.f * acc[s][r];
      d2 = fmaxf(d2, 0.f);
      float d = (d2 > 1e-12f) ? sqrtf(d2) : 0.f;
      mx = fmaxf(mx, d);
      D[(size_t)i * NN + j] = d;
    }
  }
  for (int off = 32; off > 0; off >>= 1) mx = fmaxf(mx, __shfl_down(mx, off, 64));
  __shared__ float wmax[4];
  if (lane == 0) wmax[w] = mx;
  __syncthreads();
  if (t == 0) {
    float mm = fmaxf(fmaxf(wmax[0], wmax[1]), fmaxf(wmax[2], wmax[3]));
    atomicMax(&caps[g], __float_as_uint(mm));
  }
}

// ---------- Boruvka init ----------
__global__ void k_binit(int* __restrict__ comp, unsigned long long* __restrict__ compbest,
                        int* __restrict__ mstcnt, int* __restrict__ ncomp) {
  int i = blockIdx.x * blockDim.x + threadIdx.x;
  if (i >= 2 * NN) return;
  comp[i] = i & (NN - 1);
  compbest[i] = ~0ull;
  if ((i & (NN - 1)) == 0) {
    mstcnt[i >> 12] = 0;
    ncomp[i >> 12] = NN;
  }
}

// ---------- Boruvka step 1: per-row min edge leaving own component ----------
// key = (weight_bits << 24) | (v << 12) | j : globally unique => only 2-cycles
__global__ __launch_bounds__(256) void k_minedge(const float* __restrict__ Dbase,
                                                 const int* __restrict__ comp_base,
                                                 unsigned long long* __restrict__ compbest_base,
                                                 const int* __restrict__ ncomp) {
  int g = blockIdx.y;
  if (ncomp[g] == 1) return;
  int v = blockIdx.x;
  const float* row = Dbase + ((size_t)g * NN + (size_t)v) * NN;
  const int* comp = comp_base + g * NN;
  unsigned long long* cbest = compbest_base + (size_t)g * NN;
  int cv = comp[v];
  int t = threadIdx.x;
  unsigned long long best = ~0ull;
  for (int j = t; j < NN; j += 256) {
    if (comp[j] != cv) {
      unsigned long long key = ((unsigned long long)__float_as_uint(row[j]) << 24) |
                               ((unsigned)v << 12) | (unsigned)j;
      if (key < best) best = key;
    }
  }
  for (int off = 32; off > 0; off >>= 1) {
    unsigned long long o = __shfl_down(best, off, 64);
    if (o < best) best = o;
  }
  __shared__ unsigned long long wmin[4];
  if ((t & 63) == 0) wmin[t >> 6] = best;
  __syncthreads();
  if (t == 0) {
    unsigned long long bb = wmin[0];
    for (int w = 1; w < 4; ++w)
      if (wmin[w] < bb) bb = wmin[w];
    if (bb != ~0ull) atomicMin(&cbest[cv], bb);
  }
}

// ---------- Boruvka step 2: hook/contract ----------
__global__ __launch_bounds__(1024) void k_hook(unsigned long long* __restrict__ compbest_base,
                                               int* __restrict__ comp_base,
                                               float* __restrict__ mstw_base,
                                               int* __restrict__ mstcnt,
                                               int* __restrict__ ncomp) {
  int g = blockIdx.x;
  if (ncomp[g] == 1) return;
  unsigned long long* cb = compbest_base + (size_t)g * NN;
  int* comp = comp_base + g * NN;
  float* mstw = mstw_base + g * (NN - 1);
  __shared__ int par[NN];
  __shared__ unsigned char live[NN];
  __shared__ int newcnt;
  int t = threadIdx.x;
  if (t == 0) newcnt = 0;
  for (int c = t; c < NN; c += 1024) {
    unsigned long long key = cb[c];
    bool a = (key != ~0ull);
    live[c] = a ? 1 : 0;
    int p = c;
    if (a) {
      int j = (int)(key & 0xfffull);
      p = comp[j];
    }
    par[c] = p;
  }
  __syncthreads();
  for (int c = t; c < NN; c += 1024) {
    int p = par[c];
    if (p != c && par[p] == c && c < p) par[c] = c;
  }
  __syncthreads();
  for (int c = t; c < NN; c += 1024) {
    if (live[c] && par[c] != c) {
      unsigned long long key = cb[c];
      float w = __uint_as_float((unsigned)(key >> 24));
      int slot = atomicAdd(&mstcnt[g], 1);
      mstw[slot] = w;
    }
  }
  __syncthreads();
  for (int it = 0; it < 12; ++it) {
    int np[NN / 1024];
    for (int c = t, k = 0; c < NN; c += 1024, ++k) np[k] = par[par[c]];
    __syncthreads();
    for (int c = t, k = 0; c < NN; c += 1024, ++k) par[c] = np[k];
    __syncthreads();
  }
  int cnt = 0;
  for (int c = t; c < NN; c += 1024)
    if (live[c] && par[c] == c) cnt++;
  for (int off = 32; off > 0; off >>= 1) cnt += __shfl_down(cnt, off, 64);
  if ((t & 63) == 0 && cnt) atomicAdd(&newcnt, cnt);
  for (int v = t; v < NN; v += 1024) comp[v] = par[comp[v]];
  for (int c = t; c < NN; c += 1024) cb[c] = ~0ull;
  __syncthreads();
  if (t == 0) ncomp[g] = newcnt;
}

// ---------- histogram: upper triangle only (each unordered pair once) ----------
// block x handles rows x and NN-1-x: exactly NN-1 elements, coalesced.
__global__ __launch_bounds__(256) void k_hist(const float* __restrict__ Dbase,
                                              const unsigned* __restrict__ caps,
                                              unsigned* __restrict__ histbase) {
  int g = blockIdx.y;
  const float* D = Dbase + (size_t)g * NN * NN;
  unsigned* hist = histbase + (size_t)g * NBINS;
  float cap = __uint_as_float(caps[g]);
  float capmax = fmaxf(__uint_as_float(caps[0]), __uint_as_float(caps[1]));
  float scale = (float)NBINS / capmax;
  int x = blockIdx.x;
  int r1 = x, r2 = NN - 1 - x;
  const float* row1 = D + (size_t)r1 * NN;
  const float* row2 = D + (size_t)r2 * NN;
  for (int j = r1 + 1 + threadIdx.x; j < NN; j += 256)
    atomicAdd(&hist[bin_of(cap - row1[j], scale)], 1u);
  for (int j = r2 + 1 + threadIdx.x; j < NN; j += 256)
    atomicAdd(&hist[bin_of(cap - row2[j], scale)], 1u);
}

// ---------- move tree edges to persistence 0 ----------
__global__ void k_treefix(const float* __restrict__ twbase, const unsigned* __restrict__ caps,
                          unsigned* __restrict__ histbase) {
  int g = blockIdx.y;
  unsigned* hist = histbase + (size_t)g * NBINS;
  float cap = __uint_as_float(caps[g]);
  float capmax = fmaxf(__uint_as_float(caps[0]), __uint_as_float(caps[1]));
  float scale = (float)NBINS / capmax;
  int idx = blockIdx.x * blockDim.x + threadIdx.x;
  if (idx < NN - 1) {
    float w = twbase[g * (NN - 1) + idx];
    atomicSub(&hist[bin_of(cap - w, scale)], 1u);
    atomicAdd(&hist[0], 1u);
  }
}

// ---------- scan phase A: per-chunk sums of (H1 - H2) ----------
__global__ __launch_bounds__(256) void k_blocksum(const unsigned* __restrict__ h1,
                                                  const unsigned* __restrict__ h2,
                                                  long long* __restrict__ csum) {
  int b = blockIdx.x, t = threadIdx.x;
  int base = b * CHUNK;
  long long s = 0;
  for (int i = t; i < CHUNK; i += 256) s += (long long)(int)(h1[base + i] - h2[base + i]);
  for (int off = 32; off > 0; off >>= 1) s += __shfl_down(s, off, 64);
  __shared__ long long wsum[4];
  if ((t & 63) == 0) wsum[t >> 6] = s;
  __syncthreads();
  if (t == 0) csum[b] = wsum[0] + wsum[1] + wsum[2] + wsum[3];
}

// ---------- scan phase B ----------
__global__ __launch_bounds__(1024) void k_scanoff(const long long* __restrict__ csum,
                                                  long long* __restrict__ coffs) {
  __shared__ long long sh[NCHUNKS];
  int t = threadIdx.x;
  sh[t] = csum[t];
  __syncthreads();
  for (int off = 1; off < NCHUNKS; off <<= 1) {
    long long v = (t >= off) ? sh[t - off] : 0;
    __syncthreads();
    sh[t] += v;
    __syncthreads();
  }
  coffs[t] = sh[t] - csum[t];
}

// ---------- scan phase C: sum |running prefix| exactly ----------
__global__ __launch_bounds__(256) void k_final(const unsigned* __restrict__ h1,
                                               const unsigned* __restrict__ h2,
                                               const long long* __restrict__ coffs,
                                               unsigned long long* __restrict__ acc) {
  int b = blockIdx.x, t = threadIdx.x;
  int base = b * CHUNK + t * 16;
  long long v[16];
  long long tsum = 0;
  for (int r = 0; r < 16; ++r) {
    v[r] = (long long)(int)(h1[base + r] - h2[base + r]);
    tsum += v[r];
  }
  int lane = t & 63, wid = t >> 6;
  long long incl = tsum;
  for (int off = 1; off < 64; off <<= 1) {
    long long o = __shfl_up(incl, off, 64);
    if (lane >= off) incl += o;
  }
  __shared__ long long wtot[4];
  if (lane == 63) wtot[wid] = incl;
  __syncthreads();
  long long woff = 0;
  for (int w = 0; w < wid; ++w) woff += wtot[w];
  long long run = coffs[b] + woff + (incl - tsum);
  unsigned long long local = 0;
  for (int r = 0; r < 16; ++r) {
    run += v[r];
    local += (unsigned long long)(run < 0 ? -run : run);
  }
  for (int off = 32; off > 0; off >>= 1) local += __shfl_down(local, off, 64);
  __shared__ unsigned long long wl[4];
  if (lane == 0) wl[wid] = local;
  __syncthreads();
  if (t == 0) atomicAdd(acc, wl[0] + wl[1] + wl[2] + wl[3]);
}

// ---------- output ----------
__global__ void k_out(const unsigned long long* __restrict__ acc,
                      const unsigned* __restrict__ caps, float* __restrict__ out) {
  float capmax = fmaxf(__uint_as_float(caps[0]), __uint_as_float(caps[1]));
  double dt = (double)capmax / (double)NBINS;
  out[0] = (float)((double)(*acc) * dt);
}

__global__ void k_fail(float* out) { out[0] = -1234567.0f; }

extern "C" void kernel_launch(void* const* d_in, const int* in_sizes, int n_in,
                              void* d_out, int out_size, void* d_ws, size_t ws_size,
                              hipStream_t stream) {
  const float* x1 = (const float*)d_in[0];
  const float* x2 = (const float*)d_in[2];
  float* out = (float*)d_out;
  char* ws = (char*)d_ws;

  const size_t offD = 0;                                    // 2 * 64 MB distance matrices
  const size_t offH = 2ull * NN * NN * 4ull;                // 2 * 16 MB histograms
  const size_t offHdr = offH + 2ull * (size_t)NBINS * 4ull; // caps(8) + acc(8) + pad
  const size_t offSq = offHdr + 64;                         // 2*N row norms
  const size_t offTw = offSq + 2ull * NN * 4ull;            // 2*(N-1) MST weights
  const size_t offCs = (offTw + 2ull * (NN - 1) * 4ull + 7ull) & ~7ull;
  const size_t offCo = offCs + (size_t)NCHUNKS * 8ull;
  const size_t offCb = offCo + (size_t)NCHUNKS * 8ull;      // compbest u64[2*NN]
  const size_t offCp = offCb + 2ull * NN * 8ull;            // comp int[2*NN]
  const size_t offMeta = offCp + 2ull * NN * 4ull;          // mstcnt[2], ncomp[2]
  const size_t needed = offMeta + 64;
  if (ws_size < needed) {
    hipLaunchKernelGGL(k_fail, dim3(1), dim3(1), 0, stream, out);
    return;
  }

  float* Dbase = (float*)(ws + offD);
  unsigned* hist = (unsigned*)(ws + offH);
  // Xhi/Xlo (2 MB each) transiently occupy the head of the histogram region;
  // re-zeroed after k_dist, before k_hist.
  unsigned short* Xhi = (unsigned short*)(ws + offH);
  unsigned short* Xlo = (unsigned short*)(ws + offH + 2ull * NN * DF * 2ull);
  unsigned* caps = (unsigned*)(ws + offHdr);
  unsigned long long* acc = (unsigned long long*)(ws + offHdr + 8);
  float* sq = (float*)(ws + offSq);
  float* tw = (float*)(ws + offTw);
  long long* csum = (long long*)(ws + offCs);
  long long* coffs = (long long*)(ws + offCo);
  unsigned long long* compbest = (unsigned long long*)(ws + offCb);
  int* comp = (int*)(ws + offCp);
  int* mstcnt = (int*)(ws + offMeta);
  int* ncomp = (int*)(ws + offMeta + 8);

  // zero histograms + caps + acc
  hipMemsetAsync(ws + offH, 0, 2ull * (size_t)NBINS * 4ull + 64, stream);

  hipLaunchKernelGGL(k_rownorm, dim3((2 * NN + 255) / 256), dim3(256), 0, stream, x1, x2, sq);
  hipLaunchKernelGGL(k_split, dim3((2 * NN * DF + 255) / 256), dim3(256), 0, stream,
                     x1, x2, Xhi, Xlo);
  hipLaunchKernelGGL(k_dist, dim3(64, 64, 2), dim3(256), 0, stream, Xhi, Xlo, sq, Dbase, caps);
  // re-zero the histogram head that held Xhi/Xlo
  hipMemsetAsync(ws + offH, 0, 4ull * NN * DF * 2ull, stream);
  hipLaunchKernelGGL(k_binit, dim3((2 * NN + 255) / 256), dim3(256), 0, stream,
                     comp, compbest, mstcnt, ncomp);
  for (int r = 0; r < BORUVKA_ROUNDS; ++r) {
    hipLaunchKernelGGL(k_minedge, dim3(NN, 2), dim3(256), 0, stream,
                       Dbase, comp, compbest, ncomp);
    hipLaunchKernelGGL(k_hook, dim3(2), dim3(1024), 0, stream,
                       compbest, comp, tw, mstcnt, ncomp);
  }
  hipLaunchKernelGGL(k_hist, dim3(NN / 2, 2), dim3(256), 0, stream, Dbase, caps, hist);
  hipLaunchKernelGGL(k_treefix, dim3(16, 2), dim3(256), 0, stream, tw, caps, hist);
  hipLaunchKernelGGL(k_blocksum, dim3(NCHUNKS), dim3(256), 0, stream, hist, hist + NBINS, csum);
  hipLaunchKernelGGL(k_scanoff, dim3(1), dim3(NCHUNKS), 0, stream, csum, coffs);
  hipLaunchKernelGGL(k_final, dim3(NCHUNKS), dim3(256), 0, stream, hist, hist + NBINS, coffs, acc);
  hipLaunchKernelGGL(k_out, dim3(1), dim3(1), 0, stream, acc, caps, out);
}